// Round 7
// baseline (8001.267 us; speedup 1.0000x reference)
//
#include <hip/hip_runtime.h>
#include <math.h>

#define DM   272
#define DS   32
#define DI   544
#define DTR  17
#define SEQL 512
#define NB   2
#define ROWS 1024
#define DXZ  1088
#define NL   12
#define KP   288
#define NBLK 512
#define NTHR 256

typedef unsigned short ushort_t;
typedef __attribute__((ext_vector_type(8))) short bx8;
typedef __attribute__((ext_vector_type(4))) float fx4;

// workspace offsets (floats)
#define OFF_X     0
#define OFF_XZ    279552
#define OFF_XCT   2507776
#define OFF_DTT   3621888
#define OFF_ZT    4736000
#define OFF_BM    5850112
#define OFF_CM    5915648
#define OFF_YOT   5981184
#define OFF_Y12   7095296
#define OFF_XMP   7652352
#define OFF_DTWT  7656704
#define OFF_XNH   7878656
#define OFF_XNL   8026112
#define OFF_CNT   8173568    // reuses old ytm slot
#define OFF_WINH  9287680
#define OFF_WINL  13047808
#define OFF_WOUTH 16807936
#define OFF_WOUTL 18583552
// end: 20,359,168 floats = 81.4 MB

#define NINW  (12*2176*KP)
#define NOUTW (12*544*544)

__device__ __forceinline__ float sigmoid_fast(float x){ return 1.f/(1.f+__expf(-x)); }
__device__ __forceinline__ float softplus_f(float x){ return (x > 20.f) ? x : log1pf(__expf(x)); }

__device__ __forceinline__ void bf16split(float x, ushort_t& h, ushort_t& l){
  unsigned uh = __float_as_uint(x) & 0xffff0000u;
  h = (ushort_t)(uh >> 16);
  float r = x - __uint_as_float(uh);
  l = (ushort_t)(__float_as_uint(r) >> 16);
}

__device__ __forceinline__ float block_reduce_256(float v, volatile float* sred, int tid){
#pragma unroll
  for (int m=32; m>=1; m>>=1) v += __shfl_xor(v, m);
  __syncthreads();
  if ((tid & 63) == 0) sred[tid>>6] = v;
  __syncthreads();
  return sred[0]+sred[1]+sred[2]+sred[3];
}

// grid barrier: monotonic counter, device-scope release add + acquire spin
__device__ __forceinline__ void gbar(int* cnt, int target, int tid){
  __syncthreads();
  if (tid == 0){
    __threadfence();
    __hip_atomic_fetch_add(cnt, 1, __ATOMIC_RELEASE, __HIP_MEMORY_SCOPE_AGENT);
    while (__hip_atomic_load(cnt, __ATOMIC_ACQUIRE, __HIP_MEMORY_SCOPE_AGENT) < target)
      __builtin_amdgcn_s_sleep(8);
  }
  __syncthreads();
}

union SMem {
  struct { float xcs[8][548]; float part[8][8][84]; float dts[8][20]; } x;   // 39.7 KB
  struct { float hl[2][16][33], pl[2][16][33], Hi[2][16][33]; } s;           // 12.7 KB
  struct { ushort_t ash[32][40], asl[32][40]; } g;                           // 5.1 KB
  struct { float xm[2][DM]; float x2s[2][DM]; float sred[4]; } h;            // 4.4 KB
  float sred0[4];
};

__global__ __launch_bounds__(NTHR, 2) void k_mega(
  const float* __restrict__ x0, const float* __restrict__ yin,
  const float* __restrict__ in_w, const float* __restrict__ conv_w,
  const float* __restrict__ conv_b, const float* __restrict__ x_w,
  const float* __restrict__ dt_w, const float* __restrict__ dt_b,
  const float* __restrict__ a_log, const float* __restrict__ dskip,
  const float* __restrict__ out_w, const float* __restrict__ lamq,
  const float* __restrict__ n1w, const float* __restrict__ n2w,
  const float* __restrict__ mlpw, const float* __restrict__ mlpb,
  const float* __restrict__ pw, const float* __restrict__ pb,
  float* __restrict__ ws, float* __restrict__ outp)
{
  float* xb  = ws + OFF_X;
  float* xz  = ws + OFF_XZ;
  float* xcT = ws + OFF_XCT;
  float* dtT = ws + OFF_DTT;
  float* zT  = ws + OFF_ZT;
  float* Bm  = ws + OFF_BM;
  float* Cm  = ws + OFF_CM;
  float* yoT = ws + OFF_YOT;
  float* y12 = ws + OFF_Y12;
  float* xmp = ws + OFF_XMP;
  float* dtwT= ws + OFF_DTWT;
  ushort_t* xnh  = (ushort_t*)(ws + OFF_XNH);
  ushort_t* xnl  = (ushort_t*)(ws + OFF_XNL);
  ushort_t* winh = (ushort_t*)(ws + OFF_WINH);
  ushort_t* winl = (ushort_t*)(ws + OFF_WINL);
  ushort_t* wouth= (ushort_t*)(ws + OFF_WOUTH);
  ushort_t* woutl= (ushort_t*)(ws + OFF_WOUTL);
  int* cnt = (int*)(ws + OFF_CNT);

  const int bid = blockIdx.x, tid = threadIdx.x;
  const int wv = tid >> 6, lane = tid & 63;
  const int m16 = lane & 15, quad = lane >> 4, q8 = quad << 3;
  int bt = 0;
  __shared__ SMem sm;

  // ================= P0: weight prep + init =================
  for (int idx = bid*NTHR + tid; idx < NINW + NOUTW; idx += NBLK*NTHR){
    if (idx < NINW){
      int k = idx % KP; int row = idx / KP;
      float v = (k < DM) ? in_w[(size_t)row*DM + k] : 0.f;
      ushort_t h,l; bf16split(v,h,l);
      winh[idx]=h; winl[idx]=l;
    } else {
      int j = idx - NINW;
      float v = out_w[j];
      ushort_t h,l; bf16split(v,h,l);
      wouth[j]=h; woutl[j]=l;
    }
  }
  for (int idx = bid*NTHR + tid; idx < 24*544*DTR; idx += NBLK*NTHR){
    int ld = idx / (544*DTR); int rem = idx - ld*(544*DTR);
    int d = rem / DTR; int r = rem - d*DTR;
    dtwT[(size_t)ld*DTR*544 + (size_t)r*544 + d] = dt_w[idx];
  }
  { // init: rmsnorm of x -> xn bf16 hi/lo ; 64-lane groups, 2 rows/block
    const int g = tid >> 6, l = lane;
    if (g < 2){
      const int r = bid + (g << 9);
      float vv[5]; float ss = 0.f;
#pragma unroll
      for (int i=0;i<5;i++){
        int c = l + i*64; float v = 0.f;
        if (c < DM){ v = x0[(size_t)r*DM+c]; xb[(size_t)r*DM+c]=v; }
        vv[i]=v; ss += v*v;
      }
#pragma unroll
      for (int m=32;m>=1;m>>=1) ss += __shfl_xor(ss,m);
      float ivr = rsqrtf(ss*(1.f/DM)+1e-5f);
#pragma unroll
      for (int i=0;i<5;i++){
        int c = l + i*64;
        if (c < DM){
          ushort_t h,lo; bf16split(vv[i]*ivr*n1w[c],h,lo);
          xnh[(size_t)r*KP+c]=h; xnl[(size_t)r*KP+c]=lo;
        }
      }
      if (l < 16){ xnh[(size_t)r*KP+DM+l]=0; xnl[(size_t)r*KP+DM+l]=0; }
    }
  }
  bt++; gbar(cnt, bt*NBLK, tid);

  // ================= layers =================
  for (int layer = 0; layer < NL; layer++){
    const ushort_t* wih = winh + (size_t)layer*2176*KP;
    const ushort_t* wil = winl + (size_t)layer*2176*KP;
    const ushort_t* woh = wouth + (size_t)layer*544*544;
    const ushort_t* wol = woutl + (size_t)layer*544*544;
    const float lam_init = 0.8f - 0.6f*expf(-0.3f*(float)layer);
    const float omli = 1.f - lam_init;

    // ---- P1: in_proj MFMA (32m x 64n tiles, 1088 jobs) ----
    for (int tl = bid; tl < 1088; tl += NBLK){
      const int nt = tl >> 5;
      const int m0 = (tl & 31) << 5;
      const int dir = (nt >= 17) ? 1 : 0;
      const int n0l = (nt - dir*17) << 6;
      const int ncol = n0l + (wv<<4) + m16;
      const ushort_t* bhp = wih + (size_t)(dir*1088 + ncol)*KP + q8;
      const ushort_t* blp = wil + (size_t)(dir*1088 + ncol)*KP + q8;
      const ushort_t* ahp = xnh + (size_t)(m0 + m16)*KP + q8;
      const ushort_t* alp = xnl + (size_t)(m0 + m16)*KP + q8;
      fx4 acc0 = {0.f,0.f,0.f,0.f}, acc1 = {0.f,0.f,0.f,0.f};
      for (int k0=0;k0<KP;k0+=32){
        bx8 bh = *(const bx8*)(bhp + k0);
        bx8 bl = *(const bx8*)(blp + k0);
        bx8 a0h = *(const bx8*)(ahp + k0);
        bx8 a0l = *(const bx8*)(alp + k0);
        bx8 a1h = *(const bx8*)(ahp + (size_t)16*KP + k0);
        bx8 a1l = *(const bx8*)(alp + (size_t)16*KP + k0);
        acc0 = __builtin_amdgcn_mfma_f32_16x16x32_bf16(a0h, bh, acc0, 0,0,0);
        acc0 = __builtin_amdgcn_mfma_f32_16x16x32_bf16(a0l, bh, acc0, 0,0,0);
        acc0 = __builtin_amdgcn_mfma_f32_16x16x32_bf16(a0h, bl, acc0, 0,0,0);
        acc1 = __builtin_amdgcn_mfma_f32_16x16x32_bf16(a1h, bh, acc1, 0,0,0);
        acc1 = __builtin_amdgcn_mfma_f32_16x16x32_bf16(a1l, bh, acc1, 0,0,0);
        acc1 = __builtin_amdgcn_mfma_f32_16x16x32_bf16(a1h, bl, acc1, 0,0,0);
      }
#pragma unroll
      for (int mt=0; mt<2; mt++){
        fx4 a = mt ? acc1 : acc0;
#pragma unroll
        for (int r=0;r<4;r++){
          int rg = m0 + mt*16 + quad*4 + r;
          int b = rg >> 9, t = rg & 511;
          int ts = dir ? (511-t) : t;
          xz[(size_t)((dir*NB+b)*SEQL+ts)*DXZ + ncol] = a[r];
        }
      }
    }
    bt++; gbar(cnt, bt*NBLK, tid);

    // ---- P2: conv+silu, x_proj, dt_proj (256 jobs) ----
    if (bid < 256){
      const int seg = bid >> 6;
      const int dirx = seg >> 1;
      const int t0 = (bid & 63) << 3;
      const float* xzb = xz + (size_t)seg*SEQL*DXZ;
      const float* cw  = conv_w + ((size_t)layer*2 + dirx)*DI*4;
      const float* cb  = conv_b + ((size_t)layer*2 + dirx)*DI;
      const float* xw  = x_w + ((size_t)layer*2 + dirx)*81*DI;
      const float* dwT = dtwT + ((size_t)layer*2 + dirx)*DTR*DI;
      const float* dtb = dt_b + ((size_t)layer*2 + dirx)*DI;
      const size_t chb = (size_t)seg*DI;

      for (int j = tid; j < DI; j += NTHR){
        float4 w4 = *(const float4*)(cw + j*4);
        float bj = cb[j];
        float xv[11];
#pragma unroll
        for (int q=0; q<11; q++){
          int t = t0 + q - 3;
          xv[q] = (t >= 0) ? xzb[(size_t)t*DXZ + j] : 0.f;
        }
        float xo[8], zo[8];
#pragma unroll
        for (int rr=0; rr<8; rr++){
          float acc = bj + w4.x*xv[rr] + w4.y*xv[rr+1] + w4.z*xv[rr+2] + w4.w*xv[rr+3];
          float v = acc * sigmoid_fast(acc);
          sm.x.xcs[rr][j] = v; xo[rr] = v;
          zo[rr] = xzb[(size_t)(t0+rr)*DXZ + 544 + j];
        }
        float* xr = xcT + (chb + j)*SEQL + t0;
        *(float4*)(xr)   = make_float4(xo[0],xo[1],xo[2],xo[3]);
        *(float4*)(xr+4) = make_float4(xo[4],xo[5],xo[6],xo[7]);
        float* zr = zT + (chb + j)*SEQL + t0;
        *(float4*)(zr)   = make_float4(zo[0],zo[1],zo[2],zo[3]);
        *(float4*)(zr+4) = make_float4(zo[4],zo[5],zo[6],zo[7]);
      }
      __syncthreads();

      if (tid < 168){   // 21 e-quads x 8 k-slices of 68
        const int i = tid >> 3, ks = tid & 7;
        const int e0 = i << 2;
        const int kb = ks*68;
        const float* w0 = xw + (size_t)((e0   < 81)? e0   :80)*DI + kb;
        const float* w1 = xw + (size_t)((e0+1 < 81)? e0+1 :80)*DI + kb;
        const float* w2 = xw + (size_t)((e0+2 < 81)? e0+2 :80)*DI + kb;
        const float* w3 = xw + (size_t)((e0+3 < 81)? e0+3 :80)*DI + kb;
        float a0[8], a1[8], a2[8], a3[8];
#pragma unroll
        for (int rr=0;rr<8;rr++){ a0[rr]=0.f;a1[rr]=0.f;a2[rr]=0.f;a3[rr]=0.f; }
        for (int k=0; k<68; k+=4){
          float4 wa = *(const float4*)(w0 + k);
          float4 wb = *(const float4*)(w1 + k);
          float4 wc = *(const float4*)(w2 + k);
          float4 wd = *(const float4*)(w3 + k);
#pragma unroll
          for (int rr=0; rr<8; rr++){
            float4 x4 = *(const float4*)(&sm.x.xcs[rr][kb + k]);
            a0[rr] = fmaf(wa.x,x4.x, fmaf(wa.y,x4.y, fmaf(wa.z,x4.z, fmaf(wa.w,x4.w, a0[rr]))));
            a1[rr] = fmaf(wb.x,x4.x, fmaf(wb.y,x4.y, fmaf(wb.z,x4.z, fmaf(wb.w,x4.w, a1[rr]))));
            a2[rr] = fmaf(wc.x,x4.x, fmaf(wc.y,x4.y, fmaf(wc.z,x4.z, fmaf(wc.w,x4.w, a2[rr]))));
            a3[rr] = fmaf(wd.x,x4.x, fmaf(wd.y,x4.y, fmaf(wd.z,x4.z, fmaf(wd.w,x4.w, a3[rr]))));
          }
        }
#pragma unroll
        for (int rr=0; rr<8; rr++){
          sm.x.part[ks][rr][e0+0] = a0[rr];
          sm.x.part[ks][rr][e0+1] = a1[rr];
          sm.x.part[ks][rr][e0+2] = a2[rr];
          sm.x.part[ks][rr][e0+3] = a3[rr];
        }
      }
      __syncthreads();

      for (int idx = tid; idx < 648; idx += NTHR){
        int ta = idx / 81, e = idx - ta*81;
        float s = 0.f;
#pragma unroll
        for (int ks=0; ks<8; ks++) s += sm.x.part[ks][ta][e];
        size_t row = (size_t)seg*SEQL + t0 + ta;
        if (e < DTR)      sm.x.dts[ta][e] = s;
        else if (e < 49)  Bm[row*DS + (e-DTR)] = s;
        else              Cm[row*DS + (e-49)] = s;
      }
      __syncthreads();

      for (int c = tid; c < DI; c += NTHR){
        float w[DTR];
#pragma unroll
        for (int q=0; q<DTR; q++) w[q] = dwT[q*DI + c];
        float bv = dtb[c];
        float o[8];
#pragma unroll
        for (int rr=0; rr<8; rr++){
          float a = bv;
#pragma unroll
          for (int q=0; q<DTR; q++) a = fmaf(w[q], sm.x.dts[rr][q], a);
          o[rr] = softplus_f(a);
        }
        float* r1 = dtT + (chb + c)*SEQL + t0;
        *(float4*)(r1)   = make_float4(o[0],o[1],o[2],o[3]);
        *(float4*)(r1+4) = make_float4(o[4],o[5],o[6],o[7]);
      }
    }
    bt++; gbar(cnt, bt*NBLK, tid);

    // ---- P3: selective scan (1088 job-pairs, 2 per block) ----
    for (int pj = bid; pj < 1088; pj += NBLK){
      const int half = tid >> 7, lt = tid & 127;
      const int job = pj*2 + half;
      const int seg = job / 544;
      const int d = job - seg*544;
      const int dirx = seg >> 1;
      const int c = lt >> 3, sg = lt & 7, s0 = sg << 2;
      float A0,A1,A2,A3;
      {
        const float* al = a_log + ((size_t)layer*2 + dirx)*DI*DS + (size_t)d*DS + s0;
        A0 = -expf(al[0]); A1 = -expf(al[1]); A2 = -expf(al[2]); A3 = -expf(al[3]);
      }
      const size_t cr = ((size_t)seg*DI + d)*SEQL;
      const float* dtr = dtT + cr;
      const float* xcr = xcT + cr;
      const float* zr  = zT  + cr;
      float* yor = yoT + cr;
      const float* Bp = Bm + (size_t)seg*SEQL*DS + s0;
      const float* Cp = Cm + (size_t)seg*SEQL*DS + s0;
      float h0=0,h1=0,h2=0,h3=0,p0=1,p1=1,p2=1,p3=1;
      const int tb = c << 5;
      for (int tq=0; tq<8; tq++){
        const int t4 = tb + (tq<<2);
        float4 dt4 = *(const float4*)(dtr + t4);
        const float* dtp4 = (const float*)&dt4;
        float4 xc4 = *(const float4*)(xcr + t4);
        const float* xcp4 = (const float*)&xc4;
#pragma unroll
        for (int u=0; u<4; u++){
          float ldt = dtp4[u], lxc = xcp4[u];
          float4 B4 = *(const float4*)(Bp + (size_t)(t4+u)*DS);
          float uu = ldt*lxc;
          float e;
          e = __expf(ldt*A0); h0 = fmaf(e,h0,uu*B4.x); p0*=e;
          e = __expf(ldt*A1); h1 = fmaf(e,h1,uu*B4.y); p1*=e;
          e = __expf(ldt*A2); h2 = fmaf(e,h2,uu*B4.z); p2*=e;
          e = __expf(ldt*A3); h3 = fmaf(e,h3,uu*B4.w); p3*=e;
        }
      }
      sm.s.hl[half][c][s0]=h0; sm.s.hl[half][c][s0+1]=h1; sm.s.hl[half][c][s0+2]=h2; sm.s.hl[half][c][s0+3]=h3;
      sm.s.pl[half][c][s0]=p0; sm.s.pl[half][c][s0+1]=p1; sm.s.pl[half][c][s0+2]=p2; sm.s.pl[half][c][s0+3]=p3;
      __syncthreads();
      if (lt < 32){
        float H = 0.f;
        sm.s.Hi[half][0][lt] = 0.f;
        for (int cc=1; cc<16; cc++){
          H = fmaf(sm.s.pl[half][cc-1][lt], H, sm.s.hl[half][cc-1][lt]);
          sm.s.Hi[half][cc][lt] = H;
        }
      }
      __syncthreads();
      h0=sm.s.Hi[half][c][s0]; h1=sm.s.Hi[half][c][s0+1]; h2=sm.s.Hi[half][c][s0+2]; h3=sm.s.Hi[half][c][s0+3];
      const float dsk = dskip[((size_t)layer*2 + dirx)*DI + d];
      for (int tq=0; tq<8; tq++){
        const int t4 = tb + (tq<<2);
        float4 dt4 = *(const float4*)(dtr + t4);
        const float* dtp4 = (const float*)&dt4;
        float4 xc4 = *(const float4*)(xcr + t4);
        const float* xcp4 = (const float*)&xc4;
        float4 z4 = *(const float4*)(zr + t4);
        const float* zp4 = (const float*)&z4;
        float yv[4];
#pragma unroll
        for (int u=0; u<4; u++){
          float ldt = dtp4[u], lxc = xcp4[u];
          float4 B4 = *(const float4*)(Bp + (size_t)(t4+u)*DS);
          float4 C4 = *(const float4*)(Cp + (size_t)(t4+u)*DS);
          float uu = ldt*lxc;
          float e;
          e = __expf(ldt*A0); h0 = fmaf(e,h0,uu*B4.x);
          e = __expf(ldt*A1); h1 = fmaf(e,h1,uu*B4.y);
          e = __expf(ldt*A2); h2 = fmaf(e,h2,uu*B4.z);
          e = __expf(ldt*A3); h3 = fmaf(e,h3,uu*B4.w);
          float y = h0*C4.x + h1*C4.y + h2*C4.z + h3*C4.w;
          y += __shfl_xor(y,1); y += __shfl_xor(y,2); y += __shfl_xor(y,4);
          float z = zp4[u];
          yv[u] = fmaf(dsk, lxc, y) * (z * sigmoid_fast(z));
        }
        if (sg==0) *(float4*)(yor + t4) = make_float4(yv[0],yv[1],yv[2],yv[3]);
      }
    }
    bt++; gbar(cnt, bt*NBLK, tid);

    // ---- P4: out_proj MFMA with fused LDS transpose (320 jobs, 32t x 64n) ----
    for (int job = bid; job < 320; job += NBLK){
      const int dir = (job >= 160) ? 1 : 0;
      const int j2 = job - dir*160;
      const int nti = j2 % 5;
      const int mti = j2 / 5;
      const int n0 = nti << 6;
      const int m0 = mti << 5;
      const int seg = dir*NB + (m0 >> 9);
      const int t0 = m0 & 511;
      const int nloc = n0 + (wv<<4) + m16;
      const bool nval = nloc < DM;
      const int nrow = dir*DM + (nval ? nloc : 0);
      const ushort_t* bhp = woh + (size_t)nrow*DI + q8;
      const ushort_t* blp = wol + (size_t)nrow*DI + q8;
      fx4 acc0 = {0.f,0.f,0.f,0.f}, acc1 = {0.f,0.f,0.f,0.f};
      const int dr = tid >> 3, tc = (tid & 7) << 2;
      for (int k0=0; k0<DI; k0+=32){
        float4 v = *(const float4*)(yoT + ((size_t)(seg*DI + k0 + dr))*SEQL + t0 + tc);
        ushort_t h,l;
        bf16split(v.x,h,l); sm.g.ash[tc+0][dr]=h; sm.g.asl[tc+0][dr]=l;
        bf16split(v.y,h,l); sm.g.ash[tc+1][dr]=h; sm.g.asl[tc+1][dr]=l;
        bf16split(v.z,h,l); sm.g.ash[tc+2][dr]=h; sm.g.asl[tc+2][dr]=l;
        bf16split(v.w,h,l); sm.g.ash[tc+3][dr]=h; sm.g.asl[tc+3][dr]=l;
        __syncthreads();
        bx8 bh = *(const bx8*)(bhp + k0);
        bx8 bl = *(const bx8*)(blp + k0);
        bx8 a0h = *(const bx8*)(&sm.g.ash[m16][q8]);
        bx8 a0l = *(const bx8*)(&sm.g.asl[m16][q8]);
        bx8 a1h = *(const bx8*)(&sm.g.ash[16+m16][q8]);
        bx8 a1l = *(const bx8*)(&sm.g.asl[16+m16][q8]);
        acc0 = __builtin_amdgcn_mfma_f32_16x16x32_bf16(a0h, bh, acc0, 0,0,0);
        acc0 = __builtin_amdgcn_mfma_f32_16x16x32_bf16(a0l, bh, acc0, 0,0,0);
        acc0 = __builtin_amdgcn_mfma_f32_16x16x32_bf16(a0h, bl, acc0, 0,0,0);
        acc1 = __builtin_amdgcn_mfma_f32_16x16x32_bf16(a1h, bh, acc1, 0,0,0);
        acc1 = __builtin_amdgcn_mfma_f32_16x16x32_bf16(a1l, bh, acc1, 0,0,0);
        acc1 = __builtin_amdgcn_mfma_f32_16x16x32_bf16(a1h, bl, acc1, 0,0,0);
        __syncthreads();
      }
      if (nval){
#pragma unroll
        for (int mt=0; mt<2; mt++){
          fx4 a = mt ? acc1 : acc0;
#pragma unroll
          for (int r=0;r<4;r++){
            int rg = m0 + mt*16 + quad*4 + r;
            int b = rg >> 9, t = rg & 511;
            int ts = dir ? (511-t) : t;
            y12[(size_t)dir*ROWS*DM + (size_t)(b*SEQL+ts)*DM + nloc] = a[r];
          }
        }
      }
    }
    bt++; gbar(cnt, bt*NBLK, tid);

    // ---- P5: combine (2 rows/block) ----
    for (int r = bid; r < ROWS; r += NBLK){
      const float* y1 = y12 + (size_t)r*DM;
      const float* y2 = y12 + (size_t)ROWS*DM + (size_t)r*DM;
      const float* lq = lamq + (size_t)layer*DM;
      const float* w2 = n2w + (size_t)layer*DM;
      const float* w1n = n1w + (size_t)(((layer+1)%NL))*DM;
      float lp = lq[tid];
      if (tid < 16) lp += lq[tid+256];
      float lsum = block_reduce_256(lp, sm.sred0, tid);
      float lam = sigmoid_fast(lsum) + lam_init;
      float a0 = y1[tid] - lam*y2[tid];
      float a1 = 0.f;
      if (tid<16) a1 = y1[tid+256] - lam*y2[tid+256];
      float ss = block_reduce_256(a0*a0 + a1*a1, sm.sred0, tid);
      float rms = rsqrtf(ss*(1.f/DM) + 1e-5f);
      float xo0 = xb[(size_t)r*DM + tid] + a0*rms*w2[tid]*omli;
      float xo1 = 0.f;
      if (tid<16) xo1 = xb[(size_t)r*DM + tid+256] + a1*rms*w2[tid+256]*omli;
      xb[(size_t)r*DM+tid] = xo0;
      if (tid<16) xb[(size_t)r*DM+tid+256] = xo1;
      float ss2 = block_reduce_256(xo0*xo0 + xo1*xo1, sm.sred0, tid);
      float ivn = rsqrtf(ss2*(1.f/DM) + 1e-5f);
      {
        ushort_t h,l; bf16split(xo0*ivn*w1n[tid], h, l);
        xnh[(size_t)r*KP + tid] = h; xnl[(size_t)r*KP + tid] = l;
      }
      if (tid < 16){
        ushort_t h,l; bf16split(xo1*ivn*w1n[tid+256], h, l);
        xnh[(size_t)r*KP + tid+256] = h; xnl[(size_t)r*KP + tid+256] = l;
        xnh[(size_t)r*KP + DM + tid] = 0; xnl[(size_t)r*KP + DM + tid] = 0;
      }
      __syncthreads();
    }
    bt++; gbar(cnt, bt*NBLK, tid);
  }

  // ================= head =================
  if (bid < 16){
    const int ch = bid & 7, bq = bid >> 3;
    int t0 = ch*64;
    float s0=0.f, s1=0.f;
    for (int t=t0; t<t0+64; t++){
      const float* row = xb + (size_t)(bq*SEQL+t)*DM;
      s0 += row[tid];
      if (tid<16) s1 += row[tid+256];
    }
    xmp[(size_t)(bq*8+ch)*DM + tid] = s0;
    if (tid<16) xmp[(size_t)(bq*8+ch)*DM + tid+256] = s1;
  }
  bt++; gbar(cnt, bt*NBLK, tid);

  if (bid == 0){
    for (int idx=tid; idx<2*DM; idx+=NTHR){
      int b = idx / DM, c = idx - b*DM;
      float s=0.f;
      for (int ch=0; ch<8; ch++) s += xmp[(size_t)(b*8+ch)*DM + c];
      sm.h.xm[b][c] = s * (1.f/SEQL);
    }
    __syncthreads();
    for (int idx=tid; idx<2*DM; idx+=NTHR){
      int b = idx / DM, c = idx - b*DM;
      float acc = mlpb[c];
      const float* wr = mlpw + (size_t)c*DM;
      for (int k=0;k<DM;k++) acc += wr[k]*sm.h.xm[b][k];
      float v = fmaxf(acc, 0.f);
      sm.h.x2s[b][c] = v;
      outp[2 + b*DM + c] = v;
    }
    __syncthreads();
    for (int b=0;b<2;b++){
      float p = sm.h.x2s[b][tid]*pw[tid];
      if (tid<16) p += sm.h.x2s[b][tid+256]*pw[tid+256];
      float tot = block_reduce_256(p, sm.h.sred, tid);
      if (tid==0) outp[b] = tot + yin[b]*pw[DM] + pb[0];
    }
  }
}

// ----------------------------------------------------------------
extern "C" void kernel_launch(void* const* d_in, const int* in_sizes, int n_in,
                              void* d_out, int out_size, void* d_ws, size_t ws_size,
                              hipStream_t stream)
{
  const float* x0     = (const float*)d_in[0];
  const float* yin    = (const float*)d_in[1];
  const float* in_w   = (const float*)d_in[2];
  const float* conv_w = (const float*)d_in[3];
  const float* conv_b = (const float*)d_in[4];
  const float* x_w    = (const float*)d_in[5];
  const float* dt_w   = (const float*)d_in[6];
  const float* dt_b   = (const float*)d_in[7];
  const float* a_log  = (const float*)d_in[8];
  const float* dskip  = (const float*)d_in[9];
  const float* out_w  = (const float*)d_in[10];
  const float* lamq   = (const float*)d_in[11];
  const float* n1w    = (const float*)d_in[12];
  const float* n2w    = (const float*)d_in[13];
  const float* mlpw   = (const float*)d_in[14];
  const float* mlpb   = (const float*)d_in[15];
  const float* pw     = (const float*)d_in[16];
  const float* pb     = (const float*)d_in[17];

  float* ws = (float*)d_ws;
  hipMemsetAsync((void*)(ws + OFF_CNT), 0, 256, stream);
  k_mega<<<NBLK, NTHR, 0, stream>>>(x0, yin, in_w, conv_w, conv_b, x_w, dt_w, dt_b,
      a_log, dskip, out_w, lamq, n1w, n2w, mlpw, mlpb, pw, pb,
      ws, (float*)d_out);
}

// Round 8
// 5011.252 us; speedup vs baseline: 1.5967x; 1.5967x over previous
//
#include <hip/hip_runtime.h>
#include <math.h>

#define DM   272
#define DS   32
#define DI   544
#define DTR  17
#define SEQL 512
#define NB   2
#define ROWS 1024
#define DXZ  1088
#define NL   12
#define KP   288
#define NBLK 512
#define NTHR 256

typedef unsigned short ushort_t;
typedef __attribute__((ext_vector_type(8))) short bx8;
typedef __attribute__((ext_vector_type(4))) float fx4;

// workspace offsets (floats)
#define OFF_X     0
#define OFF_XZ    279552
#define OFF_XCT   2507776
#define OFF_DTT   3621888
#define OFF_ZT    4736000
#define OFF_BM    5850112
#define OFF_CM    5915648
#define OFF_YOT   5981184
#define OFF_Y12   7095296
#define OFF_XMP   7652352
#define OFF_DTWT  7656704
#define OFF_XNH   7878656
#define OFF_XNL   8026112
#define OFF_YTMH  8173568
#define OFF_YTML  8730624
#define OFF_WINH  9287680
#define OFF_WINL  13047808
#define OFF_WOUTH 16807936
#define OFF_WOUTL 18583552
#define OFF_FLAGS 20359168   // 512*16 ints flags + 16 ints go
// end: ~20,367,400 floats = 81.5 MB

#define NINW  (12*2176*KP)
#define NOUTW (12*544*544)

__device__ __forceinline__ float sigmoid_fast(float x){ return 1.f/(1.f+__expf(-x)); }
__device__ __forceinline__ float softplus_f(float x){ return (x > 20.f) ? x : log1pf(__expf(x)); }

__device__ __forceinline__ void bf16split(float x, ushort_t& h, ushort_t& l){
  unsigned uh = __float_as_uint(x) & 0xffff0000u;
  h = (ushort_t)(uh >> 16);
  float r = x - __uint_as_float(uh);
  l = (ushort_t)(__float_as_uint(r) >> 16);
}

__device__ __forceinline__ float block_reduce_256(float v, volatile float* sred, int tid){
#pragma unroll
  for (int m=32; m>=1; m>>=1) v += __shfl_xor(v, m);
  __syncthreads();
  if ((tid & 63) == 0) sred[tid>>6] = v;
  __syncthreads();
  return sred[0]+sred[1]+sred[2]+sred[3];
}

// grid barrier v2: relaxed spins only (no per-iteration L2 invalidation);
// one release fence before arrival, one acquire fence after the barrier.
__device__ __forceinline__ void gbar(int* flags, int* go, int bt, int bid, int tid){
  __syncthreads();
  __builtin_amdgcn_fence(__ATOMIC_RELEASE, "agent");
  if (tid == 0)
    __hip_atomic_store(&flags[bid*16], bt, __ATOMIC_RELAXED, __HIP_MEMORY_SCOPE_AGENT);
  if (bid == 0){
    for (int i = tid; i < NBLK; i += NTHR){
      while (__hip_atomic_load(&flags[i*16], __ATOMIC_RELAXED, __HIP_MEMORY_SCOPE_AGENT) < bt)
        __builtin_amdgcn_s_sleep(1);
    }
    __syncthreads();
    if (tid == 0)
      __hip_atomic_store(go, bt, __ATOMIC_RELAXED, __HIP_MEMORY_SCOPE_AGENT);
  }
  if (tid == 0){
    while (__hip_atomic_load(go, __ATOMIC_RELAXED, __HIP_MEMORY_SCOPE_AGENT) < bt)
      __builtin_amdgcn_s_sleep(2);
  }
  __syncthreads();
  __builtin_amdgcn_fence(__ATOMIC_ACQUIRE, "agent");
}

union SMem {
  struct { float xcs[8][548]; float part[8][8][84]; float dts[8][20]; } x;   // 39.6 KB
  struct { float hl[2][16][33], pl[2][16][33], Hi[2][16][33]; } s;           // 12.7 KB
  struct { float tl[32][65]; } t;                                            // 8.3 KB
  struct { float xm[2][DM]; float x2s[2][DM]; float sred[4]; } h;            // 4.4 KB
  float sred0[4];
};

__global__ __launch_bounds__(NTHR, 2) void k_mega(
  const float* __restrict__ x0, const float* __restrict__ yin,
  const float* __restrict__ in_w, const float* __restrict__ conv_w,
  const float* __restrict__ conv_b, const float* __restrict__ x_w,
  const float* __restrict__ dt_w, const float* __restrict__ dt_b,
  const float* __restrict__ a_log, const float* __restrict__ dskip,
  const float* __restrict__ out_w, const float* __restrict__ lamq,
  const float* __restrict__ n1w, const float* __restrict__ n2w,
  const float* __restrict__ mlpw, const float* __restrict__ mlpb,
  const float* __restrict__ pw, const float* __restrict__ pb,
  float* __restrict__ ws, float* __restrict__ outp)
{
  float* xb  = ws + OFF_X;
  float* xz  = ws + OFF_XZ;
  float* xcT = ws + OFF_XCT;
  float* dtT = ws + OFF_DTT;
  float* zT  = ws + OFF_ZT;
  float* Bm  = ws + OFF_BM;
  float* Cm  = ws + OFF_CM;
  float* yoT = ws + OFF_YOT;
  float* y12 = ws + OFF_Y12;
  float* xmp = ws + OFF_XMP;
  float* dtwT= ws + OFF_DTWT;
  ushort_t* xnh  = (ushort_t*)(ws + OFF_XNH);
  ushort_t* xnl  = (ushort_t*)(ws + OFF_XNL);
  ushort_t* ytmh = (ushort_t*)(ws + OFF_YTMH);
  ushort_t* ytml = (ushort_t*)(ws + OFF_YTML);
  ushort_t* winh = (ushort_t*)(ws + OFF_WINH);
  ushort_t* winl = (ushort_t*)(ws + OFF_WINL);
  ushort_t* wouth= (ushort_t*)(ws + OFF_WOUTH);
  ushort_t* woutl= (ushort_t*)(ws + OFF_WOUTL);
  int* flags = (int*)(ws + OFF_FLAGS);
  int* go    = flags + NBLK*16;

  const int bid = blockIdx.x, tid = threadIdx.x;
  const int wv = tid >> 6, lane = tid & 63;
  const int m16 = lane & 15, quad = lane >> 4, q8 = quad << 3;
  int bt = 0;
  __shared__ SMem sm;

  // ================= P0: weight prep + init =================
  for (int idx = bid*NTHR + tid; idx < NINW + NOUTW; idx += NBLK*NTHR){
    if (idx < NINW){
      int k = idx % KP; int row = idx / KP;
      float v = (k < DM) ? in_w[(size_t)row*DM + k] : 0.f;
      ushort_t h,l; bf16split(v,h,l);
      winh[idx]=h; winl[idx]=l;
    } else {
      int j = idx - NINW;
      float v = out_w[j];
      ushort_t h,l; bf16split(v,h,l);
      wouth[j]=h; woutl[j]=l;
    }
  }
  for (int idx = bid*NTHR + tid; idx < 24*544*DTR; idx += NBLK*NTHR){
    int ld = idx / (544*DTR); int rem = idx - ld*(544*DTR);
    int d = rem / DTR; int r = rem - d*DTR;
    dtwT[(size_t)ld*DTR*544 + (size_t)r*544 + d] = dt_w[idx];
  }
  {
    const int g = tid >> 6, l = lane;
    if (g < 2){
      const int r = bid + (g << 9);
      float vv[5]; float ss = 0.f;
#pragma unroll
      for (int i=0;i<5;i++){
        int c = l + i*64; float v = 0.f;
        if (c < DM){ v = x0[(size_t)r*DM+c]; xb[(size_t)r*DM+c]=v; }
        vv[i]=v; ss += v*v;
      }
#pragma unroll
      for (int m=32;m>=1;m>>=1) ss += __shfl_xor(ss,m);
      float ivr = rsqrtf(ss*(1.f/DM)+1e-5f);
#pragma unroll
      for (int i=0;i<5;i++){
        int c = l + i*64;
        if (c < DM){
          ushort_t h,lo; bf16split(vv[i]*ivr*n1w[c],h,lo);
          xnh[(size_t)r*KP+c]=h; xnl[(size_t)r*KP+c]=lo;
        }
      }
      if (l < 16){ xnh[(size_t)r*KP+DM+l]=0; xnl[(size_t)r*KP+DM+l]=0; }
    }
  }
  bt++; gbar(flags, go, bt, bid, tid);

  // ================= layers =================
  for (int layer = 0; layer < NL; layer++){
    const ushort_t* wih = winh + (size_t)layer*2176*KP;
    const ushort_t* wil = winl + (size_t)layer*2176*KP;
    const ushort_t* woh = wouth + (size_t)layer*544*544;
    const ushort_t* wol = woutl + (size_t)layer*544*544;
    const float lam_init = 0.8f - 0.6f*expf(-0.3f*(float)layer);
    const float omli = 1.f - lam_init;

    // ---- P1: in_proj MFMA (32m x 64n tiles, 1088 jobs) ----
    for (int tl = bid; tl < 1088; tl += NBLK){
      const int nt = tl >> 5;
      const int m0 = (tl & 31) << 5;
      const int dir = (nt >= 17) ? 1 : 0;
      const int n0l = (nt - dir*17) << 6;
      const int ncol = n0l + (wv<<4) + m16;
      const ushort_t* bhp = wih + (size_t)(dir*1088 + ncol)*KP + q8;
      const ushort_t* blp = wil + (size_t)(dir*1088 + ncol)*KP + q8;
      const ushort_t* ahp = xnh + (size_t)(m0 + m16)*KP + q8;
      const ushort_t* alp = xnl + (size_t)(m0 + m16)*KP + q8;
      fx4 acc0 = {0.f,0.f,0.f,0.f}, acc1 = {0.f,0.f,0.f,0.f};
      for (int k0=0;k0<KP;k0+=32){
        bx8 bh = *(const bx8*)(bhp + k0);
        bx8 bl = *(const bx8*)(blp + k0);
        bx8 a0h = *(const bx8*)(ahp + k0);
        bx8 a0l = *(const bx8*)(alp + k0);
        bx8 a1h = *(const bx8*)(ahp + (size_t)16*KP + k0);
        bx8 a1l = *(const bx8*)(alp + (size_t)16*KP + k0);
        acc0 = __builtin_amdgcn_mfma_f32_16x16x32_bf16(a0h, bh, acc0, 0,0,0);
        acc0 = __builtin_amdgcn_mfma_f32_16x16x32_bf16(a0l, bh, acc0, 0,0,0);
        acc0 = __builtin_amdgcn_mfma_f32_16x16x32_bf16(a0h, bl, acc0, 0,0,0);
        acc1 = __builtin_amdgcn_mfma_f32_16x16x32_bf16(a1h, bh, acc1, 0,0,0);
        acc1 = __builtin_amdgcn_mfma_f32_16x16x32_bf16(a1l, bh, acc1, 0,0,0);
        acc1 = __builtin_amdgcn_mfma_f32_16x16x32_bf16(a1h, bl, acc1, 0,0,0);
      }
#pragma unroll
      for (int mt=0; mt<2; mt++){
        fx4 a = mt ? acc1 : acc0;
#pragma unroll
        for (int r=0;r<4;r++){
          int rg = m0 + mt*16 + quad*4 + r;
          int b = rg >> 9, t = rg & 511;
          int ts = dir ? (511-t) : t;
          xz[(size_t)((dir*NB+b)*SEQL+ts)*DXZ + ncol] = a[r];
        }
      }
    }
    bt++; gbar(flags, go, bt, bid, tid);

    // ---- P2: conv+silu, x_proj, dt_proj (256 jobs) ----
    if (bid < 256){
      const int seg = bid >> 6;
      const int dirx = seg >> 1;
      const int t0 = (bid & 63) << 3;
      const float* xzb = xz + (size_t)seg*SEQL*DXZ;
      const float* cw  = conv_w + ((size_t)layer*2 + dirx)*DI*4;
      const float* cb  = conv_b + ((size_t)layer*2 + dirx)*DI;
      const float* xw  = x_w + ((size_t)layer*2 + dirx)*81*DI;
      const float* dwT = dtwT + ((size_t)layer*2 + dirx)*DTR*DI;
      const float* dtb = dt_b + ((size_t)layer*2 + dirx)*DI;
      const size_t chb = (size_t)seg*DI;

      for (int j = tid; j < DI; j += NTHR){
        float4 w4 = *(const float4*)(cw + j*4);
        float bj = cb[j];
        float xv[11];
#pragma unroll
        for (int q=0; q<11; q++){
          int t = t0 + q - 3;
          xv[q] = (t >= 0) ? xzb[(size_t)t*DXZ + j] : 0.f;
        }
        float xo[8], zo[8];
#pragma unroll
        for (int rr=0; rr<8; rr++){
          float acc = bj + w4.x*xv[rr] + w4.y*xv[rr+1] + w4.z*xv[rr+2] + w4.w*xv[rr+3];
          float v = acc * sigmoid_fast(acc);
          sm.x.xcs[rr][j] = v; xo[rr] = v;
          zo[rr] = xzb[(size_t)(t0+rr)*DXZ + 544 + j];
        }
        float* xr = xcT + (chb + j)*SEQL + t0;
        *(float4*)(xr)   = make_float4(xo[0],xo[1],xo[2],xo[3]);
        *(float4*)(xr+4) = make_float4(xo[4],xo[5],xo[6],xo[7]);
        float* zr = zT + (chb + j)*SEQL + t0;
        *(float4*)(zr)   = make_float4(zo[0],zo[1],zo[2],zo[3]);
        *(float4*)(zr+4) = make_float4(zo[4],zo[5],zo[6],zo[7]);
      }
      __syncthreads();

      if (tid < 168){
        const int i = tid >> 3, ks = tid & 7;
        const int e0 = i << 2;
        const int kb = ks*68;
        const float* w0 = xw + (size_t)((e0   < 81)? e0   :80)*DI + kb;
        const float* w1 = xw + (size_t)((e0+1 < 81)? e0+1 :80)*DI + kb;
        const float* w2 = xw + (size_t)((e0+2 < 81)? e0+2 :80)*DI + kb;
        const float* w3 = xw + (size_t)((e0+3 < 81)? e0+3 :80)*DI + kb;
        float a0[8], a1[8], a2[8], a3[8];
#pragma unroll
        for (int rr=0;rr<8;rr++){ a0[rr]=0.f;a1[rr]=0.f;a2[rr]=0.f;a3[rr]=0.f; }
        for (int k=0; k<68; k+=4){
          float4 wa = *(const float4*)(w0 + k);
          float4 wb = *(const float4*)(w1 + k);
          float4 wc = *(const float4*)(w2 + k);
          float4 wd = *(const float4*)(w3 + k);
#pragma unroll
          for (int rr=0; rr<8; rr++){
            float4 x4 = *(const float4*)(&sm.x.xcs[rr][kb + k]);
            a0[rr] = fmaf(wa.x,x4.x, fmaf(wa.y,x4.y, fmaf(wa.z,x4.z, fmaf(wa.w,x4.w, a0[rr]))));
            a1[rr] = fmaf(wb.x,x4.x, fmaf(wb.y,x4.y, fmaf(wb.z,x4.z, fmaf(wb.w,x4.w, a1[rr]))));
            a2[rr] = fmaf(wc.x,x4.x, fmaf(wc.y,x4.y, fmaf(wc.z,x4.z, fmaf(wc.w,x4.w, a2[rr]))));
            a3[rr] = fmaf(wd.x,x4.x, fmaf(wd.y,x4.y, fmaf(wd.z,x4.z, fmaf(wd.w,x4.w, a3[rr]))));
          }
        }
#pragma unroll
        for (int rr=0; rr<8; rr++){
          sm.x.part[ks][rr][e0+0] = a0[rr];
          sm.x.part[ks][rr][e0+1] = a1[rr];
          sm.x.part[ks][rr][e0+2] = a2[rr];
          sm.x.part[ks][rr][e0+3] = a3[rr];
        }
      }
      __syncthreads();

      for (int idx = tid; idx < 648; idx += NTHR){
        int ta = idx / 81, e = idx - ta*81;
        float s = 0.f;
#pragma unroll
        for (int ks=0; ks<8; ks++) s += sm.x.part[ks][ta][e];
        size_t row = (size_t)seg*SEQL + t0 + ta;
        if (e < DTR)      sm.x.dts[ta][e] = s;
        else if (e < 49)  Bm[row*DS + (e-DTR)] = s;
        else              Cm[row*DS + (e-49)] = s;
      }
      __syncthreads();

      for (int c = tid; c < DI; c += NTHR){
        float w[DTR];
#pragma unroll
        for (int q=0; q<DTR; q++) w[q] = dwT[q*DI + c];
        float bv = dtb[c];
        float o[8];
#pragma unroll
        for (int rr=0; rr<8; rr++){
          float a = bv;
#pragma unroll
          for (int q=0; q<DTR; q++) a = fmaf(w[q], sm.x.dts[rr][q], a);
          o[rr] = softplus_f(a);
        }
        float* r1 = dtT + (chb + c)*SEQL + t0;
        *(float4*)(r1)   = make_float4(o[0],o[1],o[2],o[3]);
        *(float4*)(r1+4) = make_float4(o[4],o[5],o[6],o[7]);
      }
    }
    bt++; gbar(flags, go, bt, bid, tid);

    // ---- P3: selective scan (1088 job-pairs) ----
    for (int pj = bid; pj < 1088; pj += NBLK){
      const int half = tid >> 7, lt = tid & 127;
      const int job = pj*2 + half;
      const int seg = job / 544;
      const int d = job - seg*544;
      const int dirx = seg >> 1;
      const int c = lt >> 3, sg = lt & 7, s0 = sg << 2;
      float A0,A1,A2,A3;
      {
        const float* al = a_log + ((size_t)layer*2 + dirx)*DI*DS + (size_t)d*DS + s0;
        A0 = -expf(al[0]); A1 = -expf(al[1]); A2 = -expf(al[2]); A3 = -expf(al[3]);
      }
      const size_t cr = ((size_t)seg*DI + d)*SEQL;
      const float* dtr = dtT + cr;
      const float* xcr = xcT + cr;
      const float* zr  = zT  + cr;
      float* yor = yoT + cr;
      const float* Bp = Bm + (size_t)seg*SEQL*DS + s0;
      const float* Cp = Cm + (size_t)seg*SEQL*DS + s0;
      float h0=0,h1=0,h2=0,h3=0,p0=1,p1=1,p2=1,p3=1;
      const int tb = c << 5;
      for (int tq=0; tq<8; tq++){
        const int t4 = tb + (tq<<2);
        float4 dt4 = *(const float4*)(dtr + t4);
        const float* dtp4 = (const float*)&dt4;
        float4 xc4 = *(const float4*)(xcr + t4);
        const float* xcp4 = (const float*)&xc4;
#pragma unroll
        for (int u=0; u<4; u++){
          float ldt = dtp4[u], lxc = xcp4[u];
          float4 B4 = *(const float4*)(Bp + (size_t)(t4+u)*DS);
          float uu = ldt*lxc;
          float e;
          e = __expf(ldt*A0); h0 = fmaf(e,h0,uu*B4.x); p0*=e;
          e = __expf(ldt*A1); h1 = fmaf(e,h1,uu*B4.y); p1*=e;
          e = __expf(ldt*A2); h2 = fmaf(e,h2,uu*B4.z); p2*=e;
          e = __expf(ldt*A3); h3 = fmaf(e,h3,uu*B4.w); p3*=e;
        }
      }
      sm.s.hl[half][c][s0]=h0; sm.s.hl[half][c][s0+1]=h1; sm.s.hl[half][c][s0+2]=h2; sm.s.hl[half][c][s0+3]=h3;
      sm.s.pl[half][c][s0]=p0; sm.s.pl[half][c][s0+1]=p1; sm.s.pl[half][c][s0+2]=p2; sm.s.pl[half][c][s0+3]=p3;
      __syncthreads();
      if (lt < 32){
        float H = 0.f;
        sm.s.Hi[half][0][lt] = 0.f;
        for (int cc=1; cc<16; cc++){
          H = fmaf(sm.s.pl[half][cc-1][lt], H, sm.s.hl[half][cc-1][lt]);
          sm.s.Hi[half][cc][lt] = H;
        }
      }
      __syncthreads();
      h0=sm.s.Hi[half][c][s0]; h1=sm.s.Hi[half][c][s0+1]; h2=sm.s.Hi[half][c][s0+2]; h3=sm.s.Hi[half][c][s0+3];
      const float dsk = dskip[((size_t)layer*2 + dirx)*DI + d];
      for (int tq=0; tq<8; tq++){
        const int t4 = tb + (tq<<2);
        float4 dt4 = *(const float4*)(dtr + t4);
        const float* dtp4 = (const float*)&dt4;
        float4 xc4 = *(const float4*)(xcr + t4);
        const float* xcp4 = (const float*)&xc4;
        float4 z4 = *(const float4*)(zr + t4);
        const float* zp4 = (const float*)&z4;
        float yv[4];
#pragma unroll
        for (int u=0; u<4; u++){
          float ldt = dtp4[u], lxc = xcp4[u];
          float4 B4 = *(const float4*)(Bp + (size_t)(t4+u)*DS);
          float4 C4 = *(const float4*)(Cp + (size_t)(t4+u)*DS);
          float uu = ldt*lxc;
          float e;
          e = __expf(ldt*A0); h0 = fmaf(e,h0,uu*B4.x);
          e = __expf(ldt*A1); h1 = fmaf(e,h1,uu*B4.y);
          e = __expf(ldt*A2); h2 = fmaf(e,h2,uu*B4.z);
          e = __expf(ldt*A3); h3 = fmaf(e,h3,uu*B4.w);
          float y = h0*C4.x + h1*C4.y + h2*C4.z + h3*C4.w;
          y += __shfl_xor(y,1); y += __shfl_xor(y,2); y += __shfl_xor(y,4);
          float z = zp4[u];
          yv[u] = fmaf(dsk, lxc, y) * (z * sigmoid_fast(z));
        }
        if (sg==0) *(float4*)(yor + t4) = make_float4(yv[0],yv[1],yv[2],yv[3]);
      }
    }
    bt++; gbar(flags, go, bt, bid, tid);

    // ---- P4: yo transpose -> time-major bf16 hi/lo (544 jobs) ----
    for (int job = bid; job < 544; job += NBLK){
      const int dtile = job % 17;
      const int rest = job / 17;
      const int ttile = rest % 8;
      const int seg = rest / 8;
      const int d0 = dtile << 5;
      const int t0 = ttile << 6;
      const int ty = tid >> 4, tx = tid & 15;
#pragma unroll
      for (int p=0; p<2; p++){
        int d = p*16 + ty;
        float4 v = *(const float4*)(yoT + ((size_t)(seg*DI + d0 + d))*SEQL + t0 + tx*4);
        sm.t.tl[d][tx*4+0]=v.x; sm.t.tl[d][tx*4+1]=v.y; sm.t.tl[d][tx*4+2]=v.z; sm.t.tl[d][tx*4+3]=v.w;
      }
      __syncthreads();
      const int tloc = tid >> 2, dq = (tid & 3) << 3;
      ushort_t h[8], l[8];
#pragma unroll
      for (int j=0;j<8;j++) bf16split(sm.t.tl[dq+j][tloc], h[j], l[j]);
      uint4 ph, pl4;
      ph.x = (unsigned)h[0] | ((unsigned)h[1]<<16);
      ph.y = (unsigned)h[2] | ((unsigned)h[3]<<16);
      ph.z = (unsigned)h[4] | ((unsigned)h[5]<<16);
      ph.w = (unsigned)h[6] | ((unsigned)h[7]<<16);
      pl4.x = (unsigned)l[0] | ((unsigned)l[1]<<16);
      pl4.y = (unsigned)l[2] | ((unsigned)l[3]<<16);
      pl4.z = (unsigned)l[4] | ((unsigned)l[5]<<16);
      pl4.w = (unsigned)l[6] | ((unsigned)l[7]<<16);
      size_t base = ((size_t)(seg*SEQL + t0 + tloc))*DI + d0 + dq;
      *(uint4*)(ytmh + base) = ph;
      *(uint4*)(ytml + base) = pl4;
      __syncthreads();
    }
    bt++; gbar(flags, go, bt, bid, tid);

    // ---- P5: out_proj MFMA from time-major bf16 (320 jobs, 32m x 64n) ----
    for (int job = bid; job < 320; job += NBLK){
      const int dir = (job >= 160) ? 1 : 0;
      const int j2 = job - dir*160;
      const int nti = j2 % 5;
      const int mti = j2 / 5;
      const int n0 = nti << 6;
      const int m0 = mti << 5;
      const int seg = dir*NB + (m0 >> 9);
      const int t0 = m0 & 511;
      const int nloc = n0 + (wv<<4) + m16;
      const bool nval = nloc < DM;
      const int nrow = dir*DM + (nval ? nloc : 0);
      const ushort_t* bhp = woh + (size_t)nrow*DI + q8;
      const ushort_t* blp = wol + (size_t)nrow*DI + q8;
      const ushort_t* ahp = ytmh + ((size_t)(seg*SEQL) + t0 + m16)*DI + q8;
      const ushort_t* alp = ytml + ((size_t)(seg*SEQL) + t0 + m16)*DI + q8;
      fx4 acc0 = {0.f,0.f,0.f,0.f}, acc1 = {0.f,0.f,0.f,0.f};
      for (int k0=0; k0<DI; k0+=32){
        bx8 bh = *(const bx8*)(bhp + k0);
        bx8 bl = *(const bx8*)(blp + k0);
        bx8 a0h = *(const bx8*)(ahp + k0);
        bx8 a0l = *(const bx8*)(alp + k0);
        bx8 a1h = *(const bx8*)(ahp + (size_t)16*DI + k0);
        bx8 a1l = *(const bx8*)(alp + (size_t)16*DI + k0);
        acc0 = __builtin_amdgcn_mfma_f32_16x16x32_bf16(a0h, bh, acc0, 0,0,0);
        acc0 = __builtin_amdgcn_mfma_f32_16x16x32_bf16(a0l, bh, acc0, 0,0,0);
        acc0 = __builtin_amdgcn_mfma_f32_16x16x32_bf16(a0h, bl, acc0, 0,0,0);
        acc1 = __builtin_amdgcn_mfma_f32_16x16x32_bf16(a1h, bh, acc1, 0,0,0);
        acc1 = __builtin_amdgcn_mfma_f32_16x16x32_bf16(a1l, bh, acc1, 0,0,0);
        acc1 = __builtin_amdgcn_mfma_f32_16x16x32_bf16(a1h, bl, acc1, 0,0,0);
      }
      if (nval){
#pragma unroll
        for (int mt=0; mt<2; mt++){
          fx4 a = mt ? acc1 : acc0;
#pragma unroll
          for (int r=0;r<4;r++){
            int rg = m0 + mt*16 + quad*4 + r;
            int b = rg >> 9, t = rg & 511;
            int ts = dir ? (511-t) : t;
            y12[(size_t)dir*ROWS*DM + (size_t)(b*SEQL+ts)*DM + nloc] = a[r];
          }
        }
      }
    }
    bt++; gbar(flags, go, bt, bid, tid);

    // ---- P6: combine (2 rows/block) ----
    for (int r = bid; r < ROWS; r += NBLK){
      const float* y1 = y12 + (size_t)r*DM;
      const float* y2 = y12 + (size_t)ROWS*DM + (size_t)r*DM;
      const float* lq = lamq + (size_t)layer*DM;
      const float* w2 = n2w + (size_t)layer*DM;
      const float* w1n = n1w + (size_t)(((layer+1)%NL))*DM;
      float lp = lq[tid];
      if (tid < 16) lp += lq[tid+256];
      float lsum = block_reduce_256(lp, sm.sred0, tid);
      float lam = sigmoid_fast(lsum) + lam_init;
      float a0 = y1[tid] - lam*y2[tid];
      float a1 = 0.f;
      if (tid<16) a1 = y1[tid+256] - lam*y2[tid+256];
      float ss = block_reduce_256(a0*a0 + a1*a1, sm.sred0, tid);
      float rms = rsqrtf(ss*(1.f/DM) + 1e-5f);
      float xo0 = xb[(size_t)r*DM + tid] + a0*rms*w2[tid]*omli;
      float xo1 = 0.f;
      if (tid<16) xo1 = xb[(size_t)r*DM + tid+256] + a1*rms*w2[tid+256]*omli;
      xb[(size_t)r*DM+tid] = xo0;
      if (tid<16) xb[(size_t)r*DM+tid+256] = xo1;
      float ss2 = block_reduce_256(xo0*xo0 + xo1*xo1, sm.sred0, tid);
      float ivn = rsqrtf(ss2*(1.f/DM) + 1e-5f);
      {
        ushort_t h,l; bf16split(xo0*ivn*w1n[tid], h, l);
        xnh[(size_t)r*KP + tid] = h; xnl[(size_t)r*KP + tid] = l;
      }
      if (tid < 16){
        ushort_t h,l; bf16split(xo1*ivn*w1n[tid+256], h, l);
        xnh[(size_t)r*KP + tid+256] = h; xnl[(size_t)r*KP + tid+256] = l;
        xnh[(size_t)r*KP + DM + tid] = 0; xnl[(size_t)r*KP + DM + tid] = 0;
      }
      __syncthreads();
    }
    bt++; gbar(flags, go, bt, bid, tid);
  }

  // ================= head =================
  if (bid < 16){
    const int ch = bid & 7, bq = bid >> 3;
    int t0 = ch*64;
    float s0=0.f, s1=0.f;
    for (int t=t0; t<t0+64; t++){
      const float* row = xb + (size_t)(bq*SEQL+t)*DM;
      s0 += row[tid];
      if (tid<16) s1 += row[tid+256];
    }
    xmp[(size_t)(bq*8+ch)*DM + tid] = s0;
    if (tid<16) xmp[(size_t)(bq*8+ch)*DM + tid+256] = s1;
  }
  bt++; gbar(flags, go, bt, bid, tid);

  if (bid == 0){
    for (int idx=tid; idx<2*DM; idx+=NTHR){
      int b = idx / DM, c = idx - b*DM;
      float s=0.f;
      for (int ch=0; ch<8; ch++) s += xmp[(size_t)(b*8+ch)*DM + c];
      sm.h.xm[b][c] = s * (1.f/SEQL);
    }
    __syncthreads();
    for (int idx=tid; idx<2*DM; idx+=NTHR){
      int b = idx / DM, c = idx - b*DM;
      float acc = mlpb[c];
      const float* wr = mlpw + (size_t)c*DM;
      for (int k=0;k<DM;k++) acc += wr[k]*sm.h.xm[b][k];
      float v = fmaxf(acc, 0.f);
      sm.h.x2s[b][c] = v;
      outp[2 + b*DM + c] = v;
    }
    __syncthreads();
    for (int b=0;b<2;b++){
      float p = sm.h.x2s[b][tid]*pw[tid];
      if (tid<16) p += sm.h.x2s[b][tid+256]*pw[tid+256];
      float tot = block_reduce_256(p, sm.h.sred, tid);
      if (tid==0) outp[b] = tot + yin[b]*pw[DM] + pb[0];
    }
  }
}

// ----------------------------------------------------------------
extern "C" void kernel_launch(void* const* d_in, const int* in_sizes, int n_in,
                              void* d_out, int out_size, void* d_ws, size_t ws_size,
                              hipStream_t stream)
{
  const float* x0     = (const float*)d_in[0];
  const float* yin    = (const float*)d_in[1];
  const float* in_w   = (const float*)d_in[2];
  const float* conv_w = (const float*)d_in[3];
  const float* conv_b = (const float*)d_in[4];
  const float* x_w    = (const float*)d_in[5];
  const float* dt_w   = (const float*)d_in[6];
  const float* dt_b   = (const float*)d_in[7];
  const float* a_log  = (const float*)d_in[8];
  const float* dskip  = (const float*)d_in[9];
  const float* out_w  = (const float*)d_in[10];
  const float* lamq   = (const float*)d_in[11];
  const float* n1w    = (const float*)d_in[12];
  const float* n2w    = (const float*)d_in[13];
  const float* mlpw   = (const float*)d_in[14];
  const float* mlpb   = (const float*)d_in[15];
  const float* pw     = (const float*)d_in[16];
  const float* pb     = (const float*)d_in[17];

  float* ws = (float*)d_ws;
  hipMemsetAsync((void*)(ws + OFF_FLAGS), 0, (NBLK*16 + 16)*sizeof(int), stream);
  k_mega<<<NBLK, NTHR, 0, stream>>>(x0, yin, in_w, conv_w, conv_b, x_w, dt_w, dt_b,
      a_log, dskip, out_w, lamq, n1w, n2w, mlpw, mlpb, pw, pb,
      ws, (float*)d_out);
}

// Round 9
// 1376.959 us; speedup vs baseline: 5.8108x; 3.6394x over previous
//
#include <hip/hip_runtime.h>
#include <math.h>

#define DM   272
#define DS   32
#define DI   544
#define DTR  17
#define SEQL 512
#define NB   2
#define ROWS 1024
#define DXZ  1088
#define NL   12
#define KP   288            // padded K for in_proj (272->288)

typedef unsigned short ushort_t;
typedef __attribute__((ext_vector_type(8))) short bx8;   // 8 bf16 (4 VGPRs)
typedef __attribute__((ext_vector_type(4))) float fx4;   // MFMA accumulator

// workspace offsets (in floats)
#define OFF_X     0          // 1024*272
#define OFF_XZ    279552     // 4*512*1088
#define OFF_XCT   2507776    // 4*544*512  (channel-major)
#define OFF_DTT   3621888
#define OFF_ZT    4736000
#define OFF_BM    5850112    // 4*512*32
#define OFF_CM    5915648
#define OFF_YOT   5981184    // 4*544*512  (channel-major)
#define OFF_Y12   7095296    // 2*1024*272
#define OFF_XMP   7652352    // 16*272
#define OFF_DTWT  7656704    // 24*17*544
#define OFF_XNH   7878656    // 1024*288 bf16
#define OFF_XNL   8026112
#define OFF_WINH  8173568    // 12*2176*288 bf16 = 3760128 floats
#define OFF_WINL  11933696
#define OFF_WOUTH 15693824   // 12*544*544 bf16 = 1775616 floats
#define OFF_WOUTL 17469440
// end: 19,245,056 floats = 77 MB

#define NINW  (12*2176*KP)
#define NOUTW (12*544*544)

__device__ __forceinline__ float sigmoid_fast(float x){ return 1.f/(1.f+__expf(-x)); }
__device__ __forceinline__ float softplus_f(float x){ return (x > 20.f) ? x : log1pf(__expf(x)); }

__device__ __forceinline__ void bf16split(float x, ushort_t& h, ushort_t& l){
  unsigned uh = __float_as_uint(x) & 0xffff0000u;
  h = (ushort_t)(uh >> 16);
  float r = x - __uint_as_float(uh);           // exact
  l = (ushort_t)(__float_as_uint(r) >> 16);
}

__device__ __forceinline__ float block_reduce_256(float v, volatile float* sred, int tid){
#pragma unroll
  for (int m=32; m>=1; m>>=1) v += __shfl_xor(v, m);
  __syncthreads();
  if ((tid & 63) == 0) sred[tid>>6] = v;
  __syncthreads();
  return sred[0]+sred[1]+sred[2]+sred[3];
}

// ---------------------------------------------------------------- prep: weight conversion + dtwT + init
// grid 1024 x 256: wave0 of block r does rmsnorm init of row r; all threads grid-stride weights
__global__ __launch_bounds__(256) void k_prep(
    const float* __restrict__ inw, const float* __restrict__ outw,
    const float* __restrict__ dtw, const float* __restrict__ x0,
    const float* __restrict__ n1w0,
    ushort_t* __restrict__ winh, ushort_t* __restrict__ winl,
    ushort_t* __restrict__ wouth, ushort_t* __restrict__ woutl,
    float* __restrict__ dtwT, float* __restrict__ xb,
    ushort_t* __restrict__ xnh, ushort_t* __restrict__ xnl)
{
  const int bid = blockIdx.x, tid = threadIdx.x;
  for (int idx = bid*256 + tid; idx < NINW + NOUTW; idx += 1024*256){
    if (idx < NINW){
      int k = idx % KP; int row = idx / KP;
      float v = (k < DM) ? inw[(size_t)row*DM + k] : 0.f;
      ushort_t h,l; bf16split(v,h,l);
      winh[idx]=h; winl[idx]=l;
    } else {
      int j = idx - NINW;
      float v = outw[j];
      ushort_t h,l; bf16split(v,h,l);
      wouth[j]=h; woutl[j]=l;
    }
  }
  for (int idx = bid*256 + tid; idx < 24*544*DTR; idx += 1024*256){
    int ld = idx / (544*DTR); int rem = idx - ld*(544*DTR);
    int d = rem / DTR; int r = rem - d*DTR;
    dtwT[(size_t)ld*DTR*544 + (size_t)r*544 + d] = dtw[idx];
  }
  if (tid < 64){
    const int r = bid, l = tid;
    float vv[5]; float ss = 0.f;
#pragma unroll
    for (int i=0;i<5;i++){
      int c = l + i*64; float v = 0.f;
      if (c < DM){ v = x0[(size_t)r*DM+c]; xb[(size_t)r*DM+c]=v; }
      vv[i]=v; ss += v*v;
    }
#pragma unroll
    for (int m=32;m>=1;m>>=1) ss += __shfl_xor(ss,m);
    float ivr = rsqrtf(ss*(1.f/DM)+1e-5f);
#pragma unroll
    for (int i=0;i<5;i++){
      int c = l + i*64;
      if (c < DM){
        ushort_t h,lo; bf16split(vv[i]*ivr*n1w0[c],h,lo);
        xnh[(size_t)r*KP+c]=h; xnl[(size_t)r*KP+c]=lo;
      }
    }
    if (l < 16){ xnh[(size_t)r*KP+DM+l]=0; xnl[(size_t)r*KP+DM+l]=0; }
  }
}

// ---------------------------------------------------------------- in_proj: split-bf16 MFMA GEMM
__global__ __launch_bounds__(256) void k_gin(
  const ushort_t* __restrict__ xnh, const ushort_t* __restrict__ xnl,
  const ushort_t* __restrict__ wh,  const ushort_t* __restrict__ wl,
  float* __restrict__ xz)
{
  const int tid = threadIdx.x;
  const int wv = tid >> 6, lane = tid & 63;
  const int m16 = lane & 15, quad = lane >> 4;
  const int q8 = quad << 3;
  const int m0 = blockIdx.x << 6;
  const int nt = blockIdx.y;                  // 0..33
  const int dir = (nt >= 17) ? 1 : 0;
  const int n0l = (nt - dir*17) << 6;
  const int ncol = n0l + (wv<<4) + m16;       // 0..1087 within dir
  const ushort_t* bhp = wh + (size_t)(dir*1088 + ncol)*KP + q8;
  const ushort_t* blp = wl + (size_t)(dir*1088 + ncol)*KP + q8;
  const ushort_t* ahp = xnh + (size_t)(m0 + m16)*KP + q8;
  const ushort_t* alp = xnl + (size_t)(m0 + m16)*KP + q8;
  fx4 acc[4];
#pragma unroll
  for (int mt=0;mt<4;mt++) acc[mt] = (fx4){0.f,0.f,0.f,0.f};
  for (int k0=0;k0<KP;k0+=32){
    bx8 bh = *(const bx8*)(bhp + k0);
    bx8 bl = *(const bx8*)(blp + k0);
#pragma unroll
    for (int mt=0;mt<4;mt++){
      bx8 ah = *(const bx8*)(ahp + (size_t)mt*16*KP + k0);
      bx8 al = *(const bx8*)(alp + (size_t)mt*16*KP + k0);
      acc[mt] = __builtin_amdgcn_mfma_f32_16x16x32_bf16(ah, bh, acc[mt], 0,0,0);
      acc[mt] = __builtin_amdgcn_mfma_f32_16x16x32_bf16(al, bh, acc[mt], 0,0,0);
      acc[mt] = __builtin_amdgcn_mfma_f32_16x16x32_bf16(ah, bl, acc[mt], 0,0,0);
    }
  }
#pragma unroll
  for (int mt=0;mt<4;mt++){
#pragma unroll
    for (int r=0;r<4;r++){
      int rg = m0 + mt*16 + quad*4 + r;
      int b = rg >> 9, t = rg & 511;
      int ts = dir ? (511 - t) : t;
      xz[((size_t)((dir*NB + b)*SEQL + ts))*DXZ + ncol] = acc[mt][r];
    }
  }
}

// ---------------------------------------------------------------- conv4+silu + x_proj + dt_proj
__global__ __launch_bounds__(512) void k_xdt(
  const float* __restrict__ xz, const float* __restrict__ cwl, const float* __restrict__ cbl,
  const float* __restrict__ xwl, const float* __restrict__ dtwTl, const float* __restrict__ dtbl,
  float* __restrict__ xcT, float* __restrict__ dtT, float* __restrict__ zT,
  float* __restrict__ Bmg, float* __restrict__ Cmg)
{
  __shared__ float xcs[8][548];
  __shared__ float part[8][8][82];
  __shared__ float dts[8][DTR];
  const int tid = threadIdx.x;
  const int blk = blockIdx.x;
  const int seg = blk >> 6;
  const int dir = seg >> 1;
  const int t0 = (blk & 63) << 3;
  const float* xzb  = xz + (size_t)seg*SEQL*DXZ;
  const float* cw   = cwl + dir*DI*4;
  const float* cb   = cbl + dir*DI;
  const float* xw   = xwl + (size_t)dir*81*DI;
  const float* dtwT = dtwTl + (size_t)dir*DTR*DI;
  const float* dtb  = dtbl + dir*DI;
  const size_t chb = (size_t)seg*DI;

  for (int j = tid; j < DI; j += 512){
    float4 w4 = *(const float4*)(cw + j*4);
    float bj = cb[j];
    float xv[11];
#pragma unroll
    for (int q=0; q<11; q++){
      int t = t0 + q - 3;
      xv[q] = (t >= 0) ? xzb[(size_t)t*DXZ + j] : 0.f;
    }
    float xo[8], zo[8];
#pragma unroll
    for (int rr=0; rr<8; rr++){
      float acc = bj + w4.x*xv[rr] + w4.y*xv[rr+1] + w4.z*xv[rr+2] + w4.w*xv[rr+3];
      float v = acc * sigmoid_fast(acc);
      xcs[rr][j] = v; xo[rr] = v;
      zo[rr] = xzb[(size_t)(t0+rr)*DXZ + 544 + j];
    }
    float* xr = xcT + (chb + j)*SEQL + t0;
    *(float4*)(xr)   = make_float4(xo[0],xo[1],xo[2],xo[3]);
    *(float4*)(xr+4) = make_float4(xo[4],xo[5],xo[6],xo[7]);
    float* zr = zT + (chb + j)*SEQL + t0;
    *(float4*)(zr)   = make_float4(zo[0],zo[1],zo[2],zo[3]);
    *(float4*)(zr+4) = make_float4(zo[4],zo[5],zo[6],zo[7]);
  }
  __syncthreads();

  if (tid < 328){
    const int i = tid >> 3, ks = tid & 7;
    const int e0 = 2*i;
    const int e1r = (e0+1 < 81) ? (e0+1) : 80;
    const int kb = ks*68;
    const float* w0 = xw + (size_t)e0*DI + kb;
    const float* w1 = xw + (size_t)e1r*DI + kb;
    float acc0[8], acc1[8];
#pragma unroll
    for (int rr=0; rr<8; rr++){ acc0[rr]=0.f; acc1[rr]=0.f; }
    for (int k=0; k<68; k+=4){
      float4 wa = *(const float4*)(w0 + k);
      float4 wb = *(const float4*)(w1 + k);
#pragma unroll
      for (int rr=0; rr<8; rr++){
        float4 x4 = *(const float4*)(&xcs[rr][kb + k]);
        acc0[rr] = fmaf(wa.x,x4.x, fmaf(wa.y,x4.y, fmaf(wa.z,x4.z, fmaf(wa.w,x4.w, acc0[rr]))));
        acc1[rr] = fmaf(wb.x,x4.x, fmaf(wb.y,x4.y, fmaf(wb.z,x4.z, fmaf(wb.w,x4.w, acc1[rr]))));
      }
    }
#pragma unroll
    for (int rr=0; rr<8; rr++){
      part[ks][rr][e0]   = acc0[rr];
      part[ks][rr][e0+1] = acc1[rr];
    }
  }
  __syncthreads();

  for (int idx=tid; idx<648; idx+=512){
    int ta = idx / 81, e = idx - ta*81;
    float s = 0.f;
#pragma unroll
    for (int ks=0; ks<8; ks++) s += part[ks][ta][e];
    size_t row = (size_t)seg*SEQL + t0 + ta;
    if (e < DTR)      dts[ta][e] = s;
    else if (e < 49)  Bmg[row*DS + (e-DTR)] = s;
    else              Cmg[row*DS + (e-49)] = s;
  }
  __syncthreads();

  {
    const int c1 = tid;
    const bool h2 = tid < 32; const int c2 = 512 + tid;
    float w1[DTR], w2[DTR];
#pragma unroll
    for (int q=0; q<DTR; q++){
      w1[q] = dtwT[q*DI + c1];
      w2[q] = h2 ? dtwT[q*DI + c2] : 0.f;
    }
    float b1 = dtb[c1], b2 = h2 ? dtb[c2] : 0.f;
    float o1[8], o2[8];
#pragma unroll
    for (int rr=0; rr<8; rr++){
      float a1=b1, a2=b2;
#pragma unroll
      for (int q=0; q<DTR; q++){
        float dv = dts[rr][q];
        a1 = fmaf(w1[q],dv,a1); a2 = fmaf(w2[q],dv,a2);
      }
      o1[rr]=softplus_f(a1); o2[rr]=softplus_f(a2);
    }
    float* r1 = dtT + (chb + c1)*SEQL + t0;
    *(float4*)(r1)   = make_float4(o1[0],o1[1],o1[2],o1[3]);
    *(float4*)(r1+4) = make_float4(o1[4],o1[5],o1[6],o1[7]);
    if (h2){
      float* r2 = dtT + (chb + c2)*SEQL + t0;
      *(float4*)(r2)   = make_float4(o2[0],o2[1],o2[2],o2[3]);
      *(float4*)(r2+4) = make_float4(o2[4],o2[5],o2[6],o2[7]);
    }
  }
}

// ---------------------------------------------------------------- chunked selective scan + gate
__global__ __launch_bounds__(128) void k_scan(
  const float* __restrict__ dtT, const float* __restrict__ xcT,
  const float* __restrict__ Bmg, const float* __restrict__ Cmg,
  const float* __restrict__ alogl, const float* __restrict__ dskl,
  const float* __restrict__ zT, float* __restrict__ yoT)
{
  __shared__ float hl[16][33], pl[16][33], Hi[16][33];
  const int d = blockIdx.x, b = blockIdx.y, dir = blockIdx.z;
  const int seg = dir*NB + b;
  const int tid = threadIdx.x;
  const int c = tid >> 3, sg = tid & 7, s0 = sg << 2;
  float A0,A1,A2,A3;
  {
    const float* al = alogl + (size_t)(dir*DI + d)*DS + s0;
    A0 = -expf(al[0]); A1 = -expf(al[1]); A2 = -expf(al[2]); A3 = -expf(al[3]);
  }
  const size_t cr = ((size_t)seg*DI + d)*SEQL;
  const float* dtr = dtT + cr;
  const float* xcr = xcT + cr;
  const float* zr  = zT  + cr;
  float* yor = yoT + cr;
  const float* Bp = Bmg + (size_t)seg*SEQL*DS + s0;
  const float* Cp = Cmg + (size_t)seg*SEQL*DS + s0;
  float h0=0,h1=0,h2=0,h3=0,p0=1,p1=1,p2=1,p3=1;
  const int tb = c << 5;
  for (int tq=0; tq<8; tq++){
    const int t4 = tb + (tq<<2);
    float4 dt4 = *(const float4*)(dtr + t4);
    const float* dtp4 = (const float*)&dt4;
    float4 xc4 = *(const float4*)(xcr + t4);
    const float* xcp4 = (const float*)&xc4;
#pragma unroll
    for (int u=0; u<4; u++){
      float ldt = dtp4[u], lxc = xcp4[u];
      float4 B4 = *(const float4*)(Bp + (size_t)(t4+u)*DS);
      float uu = ldt*lxc;
      float e;
      e = __expf(ldt*A0); h0 = fmaf(e,h0,uu*B4.x); p0*=e;
      e = __expf(ldt*A1); h1 = fmaf(e,h1,uu*B4.y); p1*=e;
      e = __expf(ldt*A2); h2 = fmaf(e,h2,uu*B4.z); p2*=e;
      e = __expf(ldt*A3); h3 = fmaf(e,h3,uu*B4.w); p3*=e;
    }
  }
  hl[c][s0]=h0; hl[c][s0+1]=h1; hl[c][s0+2]=h2; hl[c][s0+3]=h3;
  pl[c][s0]=p0; pl[c][s0+1]=p1; pl[c][s0+2]=p2; pl[c][s0+3]=p3;
  __syncthreads();
  if (tid < 32){
    float H = 0.f;
    Hi[0][tid] = 0.f;
    for (int cc=1; cc<16; cc++){
      H = fmaf(pl[cc-1][tid], H, hl[cc-1][tid]);
      Hi[cc][tid] = H;
    }
  }
  __syncthreads();
  h0=Hi[c][s0]; h1=Hi[c][s0+1]; h2=Hi[c][s0+2]; h3=Hi[c][s0+3];
  const float dsk = dskl[dir*DI + d];
  for (int tq=0; tq<8; tq++){
    const int t4 = tb + (tq<<2);
    float4 dt4 = *(const float4*)(dtr + t4);
    const float* dtp4 = (const float*)&dt4;
    float4 xc4 = *(const float4*)(xcr + t4);
    const float* xcp4 = (const float*)&xc4;
    float4 z4 = *(const float4*)(zr + t4);
    const float* zp4 = (const float*)&z4;
    float yv[4];
#pragma unroll
    for (int u=0; u<4; u++){
      float ldt = dtp4[u], lxc = xcp4[u];
      float4 B4 = *(const float4*)(Bp + (size_t)(t4+u)*DS);
      float4 C4 = *(const float4*)(Cp + (size_t)(t4+u)*DS);
      float uu = ldt*lxc;
      float e;
      e = __expf(ldt*A0); h0 = fmaf(e,h0,uu*B4.x);
      e = __expf(ldt*A1); h1 = fmaf(e,h1,uu*B4.y);
      e = __expf(ldt*A2); h2 = fmaf(e,h2,uu*B4.z);
      e = __expf(ldt*A3); h3 = fmaf(e,h3,uu*B4.w);
      float y = h0*C4.x + h1*C4.y + h2*C4.z + h3*C4.w;
      y += __shfl_xor(y,1); y += __shfl_xor(y,2); y += __shfl_xor(y,4);
      float z = zp4[u];
      yv[u] = fmaf(dsk, lxc, y) * (z * sigmoid_fast(z));
    }
    if (sg==0) *(float4*)(yor + t4) = make_float4(yv[0],yv[1],yv[2],yv[3]);
  }
}

// ---------------------------------------------------------------- out_proj MFMA with fused in-LDS transpose
// grid (16,5,2), 256 thr; per K-chunk: stage 64t x 32k bf16 hi/lo via LDS, then MFMA
__global__ __launch_bounds__(256) void k_gout2(
  const float* __restrict__ yoT,
  const ushort_t* __restrict__ wh, const ushort_t* __restrict__ wl,
  float* __restrict__ y12)
{
  __shared__ ushort_t ash[64][72];   // 144 B row stride: b128-aligned, conflict-free reads
  __shared__ ushort_t asl[64][72];
  const int tid = threadIdx.x;
  const int wv = tid >> 6, lane = tid & 63;
  const int m16 = lane & 15, quad = lane >> 4, q8 = quad << 3;
  const int m0 = blockIdx.x << 6;     // 64 time-rows
  const int n0 = blockIdx.y << 6;
  const int dir = blockIdx.z;
  const int seg = dir*NB + (m0 >> 9);
  const int t0 = m0 & 511;
  const int nloc = n0 + (wv<<4) + m16;
  const bool nval = nloc < DM;
  const int nrow = dir*DM + (nval ? nloc : 0);
  const ushort_t* bhp = wh + (size_t)nrow*DI + q8;
  const ushort_t* blp = wl + (size_t)nrow*DI + q8;
  const int tt = tid & 63;            // t within tile (wave covers all 64)
  const int kq = tid >> 6;            // k-octet (wave id)
  const float* yob = yoT + (size_t)seg*DI*SEQL + t0 + tt;
  fx4 acc[4];
#pragma unroll
  for (int mt=0;mt<4;mt++) acc[mt] = (fx4){0.f,0.f,0.f,0.f};

  float vbuf[8];
#pragma unroll
  for (int i=0;i<8;i++) vbuf[i] = yob[(size_t)(kq*8 + i)*SEQL];

  for (int k0=0; k0<DI; k0+=32){
    ushort_t h8[8], l8[8];
#pragma unroll
    for (int i=0;i<8;i++) bf16split(vbuf[i], h8[i], l8[i]);
    uint4 ph, pl;
    ph.x = (unsigned)h8[0] | ((unsigned)h8[1]<<16);
    ph.y = (unsigned)h8[2] | ((unsigned)h8[3]<<16);
    ph.z = (unsigned)h8[4] | ((unsigned)h8[5]<<16);
    ph.w = (unsigned)h8[6] | ((unsigned)h8[7]<<16);
    pl.x = (unsigned)l8[0] | ((unsigned)l8[1]<<16);
    pl.y = (unsigned)l8[2] | ((unsigned)l8[3]<<16);
    pl.z = (unsigned)l8[4] | ((unsigned)l8[5]<<16);
    pl.w = (unsigned)l8[6] | ((unsigned)l8[7]<<16);
    __syncthreads();                       // previous chunk's frag reads done
    *(uint4*)(&ash[tt][kq*8]) = ph;
    *(uint4*)(&asl[tt][kq*8]) = pl;
    __syncthreads();
    if (k0 + 32 < DI){
#pragma unroll
      for (int i=0;i<8;i++) vbuf[i] = yob[(size_t)(k0 + 32 + kq*8 + i)*SEQL];
    }
    bx8 bh = *(const bx8*)(bhp + k0);
    bx8 bl = *(const bx8*)(blp + k0);
#pragma unroll
    for (int mt=0;mt<4;mt++){
      bx8 ah = *(const bx8*)(&ash[mt*16 + m16][q8]);
      bx8 al = *(const bx8*)(&asl[mt*16 + m16][q8]);
      acc[mt] = __builtin_amdgcn_mfma_f32_16x16x32_bf16(ah, bh, acc[mt], 0,0,0);
      acc[mt] = __builtin_amdgcn_mfma_f32_16x16x32_bf16(al, bh, acc[mt], 0,0,0);
      acc[mt] = __builtin_amdgcn_mfma_f32_16x16x32_bf16(ah, bl, acc[mt], 0,0,0);
    }
  }
  if (nval){
#pragma unroll
    for (int mt=0;mt<4;mt++){
#pragma unroll
      for (int r=0;r<4;r++){
        int rg = m0 + mt*16 + quad*4 + r;
        int b = rg >> 9, t = rg & 511;
        int ts = dir ? (511 - t) : t;
        y12[(size_t)dir*ROWS*DM + ((size_t)(b*SEQL + ts))*DM + nloc] = acc[mt][r];
      }
    }
  }
}

// ---------------------------------------------------------------- combine: lam, rmsnorm, residual, next xn
__global__ __launch_bounds__(256) void k_combine(
  const float* __restrict__ y12, const float* __restrict__ lamq,
  const float* __restrict__ n2w, float* __restrict__ xb,
  const float* __restrict__ n1wn, ushort_t* __restrict__ xnh, ushort_t* __restrict__ xnl,
  float lam_init, float omli)
{
  __shared__ float sred[4];
  const int tid = threadIdx.x;
  const int r = blockIdx.x;
  const float* y1 = y12 + (size_t)r*DM;
  const float* y2 = y12 + (size_t)ROWS*DM + (size_t)r*DM;
  float lp = lamq[tid];
  if (tid < 16) lp += lamq[tid+256];
  float lsum = block_reduce_256(lp, sred, tid);
  float lam = sigmoid_fast(lsum) + lam_init;
  float a0 = y1[tid] - lam*y2[tid];
  float a1 = 0.f;
  if (tid<16) a1 = y1[tid+256] - lam*y2[tid+256];
  float ss = block_reduce_256(a0*a0 + a1*a1, sred, tid);
  float rms = rsqrtf(ss*(1.f/DM) + 1e-5f);
  float xo0 = xb[(size_t)r*DM + tid] + a0*rms*n2w[tid]*omli;
  float xo1 = 0.f;
  if (tid<16) xo1 = xb[(size_t)r*DM + tid+256] + a1*rms*n2w[tid+256]*omli;
  xb[(size_t)r*DM+tid] = xo0;
  if (tid<16) xb[(size_t)r*DM+tid+256] = xo1;
  float ss2 = block_reduce_256(xo0*xo0 + xo1*xo1, sred, tid);
  float ivn = rsqrtf(ss2*(1.f/DM) + 1e-5f);
  {
    ushort_t h,l; bf16split(xo0*ivn*n1wn[tid], h, l);
    xnh[(size_t)r*KP + tid] = h; xnl[(size_t)r*KP + tid] = l;
  }
  if (tid < 16){
    ushort_t h,l; bf16split(xo1*ivn*n1wn[tid+256], h, l);
    xnh[(size_t)r*KP + tid+256] = h; xnl[(size_t)r*KP + tid+256] = l;
    xnh[(size_t)r*KP + DM + tid] = 0; xnl[(size_t)r*KP + DM + tid] = 0;
  }
}

// ---------------------------------------------------------------- head
__global__ __launch_bounds__(256) void k_head1(const float* __restrict__ xb, float* __restrict__ xmp){
  int ch = blockIdx.x, b = blockIdx.y, tid = threadIdx.x;
  int t0 = ch*64;
  float s0=0.f, s1=0.f;
  for (int t=t0; t<t0+64; t++){
    const float* row = xb + (size_t)(b*SEQL+t)*DM;
    s0 += row[tid];
    if (tid<16) s1 += row[tid+256];
  }
  xmp[(size_t)(b*8+ch)*DM + tid] = s0;
  if (tid<16) xmp[(size_t)(b*8+ch)*DM + tid+256] = s1;
}

__global__ __launch_bounds__(256) void k_head2(
  const float* __restrict__ xmp, const float* __restrict__ yin,
  const float* __restrict__ mlpw, const float* __restrict__ mlpb,
  const float* __restrict__ pw, const float* __restrict__ pb,
  float* __restrict__ out)
{
  __shared__ float xm[2][DM];
  __shared__ float x2s[2][DM];
  __shared__ float sred[4];
  int tid = threadIdx.x;
  for (int idx=tid; idx<2*DM; idx+=256){
    int b = idx / DM, c = idx - b*DM;
    float s=0.f;
    for (int ch=0; ch<8; ch++) s += xmp[(size_t)(b*8+ch)*DM + c];
    xm[b][c] = s * (1.f/SEQL);
  }
  __syncthreads();
  for (int idx=tid; idx<2*DM; idx+=256){
    int b = idx / DM, c = idx - b*DM;
    float acc = mlpb[c];
    const float* wr = mlpw + (size_t)c*DM;
    for (int k=0;k<DM;k++) acc += wr[k]*xm[b][k];
    float v = fmaxf(acc, 0.f);
    x2s[b][c] = v;
    out[2 + b*DM + c] = v;
  }
  __syncthreads();
  for (int b=0;b<2;b++){
    float p = x2s[b][tid]*pw[tid];
    if (tid<16) p += x2s[b][tid+256]*pw[tid+256];
    float tot = block_reduce_256(p, sred, tid);
    if (tid==0) out[b] = tot + yin[b]*pw[DM] + pb[0];
  }
}

// ----------------------------------------------------------------
extern "C" void kernel_launch(void* const* d_in, const int* in_sizes, int n_in,
                              void* d_out, int out_size, void* d_ws, size_t ws_size,
                              hipStream_t stream)
{
  const float* x0     = (const float*)d_in[0];
  const float* yin    = (const float*)d_in[1];
  const float* in_w   = (const float*)d_in[2];
  const float* conv_w = (const float*)d_in[3];
  const float* conv_b = (const float*)d_in[4];
  const float* x_w    = (const float*)d_in[5];
  const float* dt_w   = (const float*)d_in[6];
  const float* dt_b   = (const float*)d_in[7];
  const float* a_log  = (const float*)d_in[8];
  const float* dskip  = (const float*)d_in[9];
  const float* out_w  = (const float*)d_in[10];
  const float* lamq   = (const float*)d_in[11];
  const float* n1w    = (const float*)d_in[12];
  const float* n2w    = (const float*)d_in[13];
  const float* mlpw   = (const float*)d_in[14];
  const float* mlpb   = (const float*)d_in[15];
  const float* pw     = (const float*)d_in[16];
  const float* pb     = (const float*)d_in[17];

  float* ws  = (float*)d_ws;
  float* xb  = ws + OFF_X;
  float* xz  = ws + OFF_XZ;
  float* xcT = ws + OFF_XCT;
  float* dtT = ws + OFF_DTT;
  float* zT  = ws + OFF_ZT;
  float* Bm  = ws + OFF_BM;
  float* Cm  = ws + OFF_CM;
  float* yoT = ws + OFF_YOT;
  float* y12 = ws + OFF_Y12;
  float* xmp = ws + OFF_XMP;
  float* dtwT= ws + OFF_DTWT;
  ushort_t* xnh  = (ushort_t*)(ws + OFF_XNH);
  ushort_t* xnl  = (ushort_t*)(ws + OFF_XNL);
  ushort_t* winh = (ushort_t*)(ws + OFF_WINH);
  ushort_t* winl = (ushort_t*)(ws + OFF_WINL);
  ushort_t* wouth= (ushort_t*)(ws + OFF_WOUTH);
  ushort_t* woutl= (ushort_t*)(ws + OFF_WOUTL);
  float* outp = (float*)d_out;

  k_prep<<<1024, 256, 0, stream>>>(in_w, out_w, dt_w, x0, n1w,
      winh, winl, wouth, woutl, dtwT, xb, xnh, xnl);
  for (int i=0;i<NL;i++){
    float lam_init = 0.8f - 0.6f*expf(-0.3f*(float)i);
    k_gin<<<dim3(16,34), 256, 0, stream>>>(xnh, xnl,
        winh + (size_t)i*2176*KP, winl + (size_t)i*2176*KP, xz);
    k_xdt<<<256, 512, 0, stream>>>(xz,
        conv_w + (size_t)i*2*DI*4, conv_b + (size_t)i*2*DI,
        x_w + (size_t)i*2*81*DI, dtwT + (size_t)i*2*DTR*DI, dt_b + (size_t)i*2*DI,
        xcT, dtT, zT, Bm, Cm);
    k_scan<<<dim3(DI,NB,2), 128, 0, stream>>>(dtT, xcT, Bm, Cm,
        a_log + (size_t)i*2*DI*DS, dskip + (size_t)i*2*DI, zT, yoT);
    k_gout2<<<dim3(16,5,2), 256, 0, stream>>>(yoT,
        wouth + (size_t)i*544*544, woutl + (size_t)i*544*544, y12);
    k_combine<<<ROWS, 256, 0, stream>>>(y12, lamq + (size_t)i*DM, n2w + (size_t)i*DM,
        xb, n1w + (size_t)((i+1)%NL)*DM, xnh, xnl, lam_init, 1.f - lam_init);
  }
  k_head1<<<dim3(8,2), 256, 0, stream>>>(xb, xmp);
  k_head2<<<1, 256, 0, stream>>>(xmp, yin, mlpw, mlpb, pw, pb, outp);
}